// Round 2
// baseline (1573.149 us; speedup 1.0000x reference)
//
#include <hip/hip_runtime.h>
#include <stdint.h>

// ---------------- problem constants ----------------
#define T_TOK 4096
#define DIM   2048
#define NEXP  64
#define TOPK  6
#define NGRP  8
#define LGRP  4
#define INTER 512
#define SHI   1024
#define CAP   768
#define RSCALE 2.5f

typedef __attribute__((ext_vector_type(4))) float f32x4;
typedef __attribute__((ext_vector_type(4))) int   i32x4;

__device__ __forceinline__ unsigned short f2bf(float f) {
  union { float f; uint32_t u; } v; v.f = f;
  return (unsigned short)((v.u + 0x7FFFu + ((v.u >> 16) & 1u)) >> 16);  // RNE
}

// async global->LDS, 16B per lane, dest = uniform base + lane*16
__device__ __forceinline__ void gload16(const void* g, void* l) {
  __builtin_amdgcn_global_load_lds((const __attribute__((address_space(1))) void*)g,
                                   (__attribute__((address_space(3))) void*)l, 16, 0, 0);
}

// D = A(16x32) * B(32x16) + D, bf16 inputs held as i32x4 bit-pattern.
// acc chains feed SrcC only (HW-forwarded); epilogue guarded by s_nop.
__device__ __forceinline__ void mfma16(f32x4& d, i32x4 a, i32x4 b) {
  asm("v_mfma_f32_16x16x32_bf16 %0, %1, %2, %0" : "+v"(d) : "v"(a), "v"(b));
}

// ---------------- tiny init: zero the per-expert counters ----------------
__global__ void zero_counts_kernel(int* __restrict__ counts) {
  counts[threadIdx.x] = 0;
}

// ---------------- prep: fp32 -> bf16 copy of x ----------------
__global__ __launch_bounds__(256) void cvt_x_kernel(const float4* __restrict__ x,
                                                    uint2* __restrict__ xb) {
  int i = blockIdx.x * 256 + threadIdx.x;
  float4 v = x[i];
  union { unsigned short s[4]; uint2 u; } o;
  o.s[0] = f2bf(v.x); o.s[1] = f2bf(v.y); o.s[2] = f2bf(v.z); o.s[3] = f2bf(v.w);
  xb[i] = o.u;
}

// ---------------- prep: transpose + convert  src[R][C] f32 -> dst[C][R] bf16 ----------------
__global__ __launch_bounds__(256) void transpose_cvt(const float* __restrict__ src,
                                                     unsigned short* __restrict__ dst,
                                                     int R, int C) {
  __shared__ float tile[32][33];
  const size_t bo = (size_t)blockIdx.z * R * C;
  const float* s = src + bo;
  unsigned short* d = dst + bo;
  int c0 = blockIdx.x * 32, r0 = blockIdx.y * 32;
  int tx = threadIdx.x & 31, ty = threadIdx.x >> 5;  // 32 x 8
  #pragma unroll
  for (int i = ty; i < 32; i += 8) tile[i][tx] = s[(size_t)(r0 + i) * C + c0 + tx];
  __syncthreads();
  #pragma unroll
  for (int i = ty; i < 32; i += 8) d[(size_t)(c0 + i) * R + r0 + tx] = f2bf(tile[tx][i]);
}

// ---------------- gate: scores = sigmoid(x @ gw^T), pure fp32 ----------------
__global__ __launch_bounds__(256) void gate_kernel(const float* __restrict__ x,
                                                   const float* __restrict__ gw,
                                                   float* __restrict__ scores) {
  __shared__ float xs[16][68];    // 16 tokens x 64 k (padded)
  __shared__ float gsT[64][65];   // gsT[k][e]
  const int tid = threadIdx.x;
  const int t0 = blockIdx.x * 16;
  const int e = tid & 63;
  const int tg = tid >> 6;        // wave id: tokens tg*4..tg*4+3
  float acc[4] = {0.f, 0.f, 0.f, 0.f};
  for (int k0 = 0; k0 < DIM; k0 += 64) {
    {
      int r = tid >> 4, c4 = (tid & 15) * 4;
      *(float4*)&xs[r][c4] = *(const float4*)&x[(size_t)(t0 + r) * DIM + k0 + c4];
      #pragma unroll
      for (int jj = 0; jj < 16; ++jj) {
        int id = tid + jj * 256;
        int er = id >> 6, c = id & 63;
        gsT[c][er] = gw[(size_t)er * DIM + k0 + c];
      }
    }
    __syncthreads();
    #pragma unroll
    for (int k = 0; k < 64; k += 4) {
      float g0 = gsT[k][e], g1 = gsT[k + 1][e], g2 = gsT[k + 2][e], g3 = gsT[k + 3][e];
      #pragma unroll
      for (int j = 0; j < 4; ++j) {
        float4 xv = *(const float4*)&xs[tg * 4 + j][k];
        acc[j] += xv.x * g0 + xv.y * g1 + xv.z * g2 + xv.w * g3;
      }
    }
    __syncthreads();
  }
  #pragma unroll
  for (int j = 0; j < 4; ++j)
    scores[(size_t)(t0 + tg * 4 + j) * NEXP + e] = 1.f / (1.f + expf(-acc[j]));
}

// ---------------- routing: group-limited top-k, slot assignment ----------------
__global__ __launch_bounds__(256) void route_kernel(const float* __restrict__ scores,
                                                    int* __restrict__ counts,
                                                    int* __restrict__ tok_list,
                                                    float* __restrict__ wt_list) {
  int t = blockIdx.x * 256 + threadIdx.x;
  float sc[64];
  #pragma unroll
  for (int i = 0; i < 16; ++i) {
    float4 v = ((const float4*)(scores + (size_t)t * NEXP))[i];
    sc[4 * i] = v.x; sc[4 * i + 1] = v.y; sc[4 * i + 2] = v.z; sc[4 * i + 3] = v.w;
  }
  float gsc[8];
  #pragma unroll
  for (int g = 0; g < 8; ++g) {
    float m = sc[g * 8];
    #pragma unroll
    for (int i = 1; i < 8; ++i) m = fmaxf(m, sc[g * 8 + i]);
    gsc[g] = m;
  }
  unsigned gm = 0;
  #pragma unroll
  for (int s = 0; s < LGRP; ++s) {   // top-4 groups, ties -> lowest index
    float best = -1e30f; int bi = 0;
    #pragma unroll
    for (int g = 0; g < 8; ++g) {
      bool ok = !((gm >> g) & 1u);
      if (ok && gsc[g] > best) { best = gsc[g]; bi = g; }
    }
    gm |= 1u << bi;
  }
  unsigned long long em = 0;
  int eidx[TOPK]; float ev[TOPK]; float sum = 0.f;
  #pragma unroll
  for (int s = 0; s < TOPK; ++s) {   // top-6 experts among selected groups
    float best = -1e30f; int bi = 0;
    #pragma unroll
    for (int e = 0; e < 64; ++e) {
      bool ok = ((gm >> (e >> 3)) & 1u) && !((em >> e) & 1ull);
      float v = ok ? sc[e] : -1e30f;
      if (v > best) { best = v; bi = e; }
    }
    em |= 1ull << bi;
    eidx[s] = bi; ev[s] = best; sum += best;
  }
  float inv = RSCALE / sum;
  #pragma unroll
  for (int s = 0; s < TOPK; ++s) {
    int e = eidx[s];
    int slot = atomicAdd(&counts[e], 1);
    if (slot < CAP) {
      tok_list[e * CAP + slot] = t;
      wt_list[e * CAP + slot] = ev[s] * inv;
    }
  }
}

// ============ GEMM 1: C = A[128xK] * [B1|B3][K x 64+64], epi: H = silu(C1)*C2 ============
// EXPERT: A rows gathered via tok_list, B per expert, H[E][CAP][INTER]
// !EXPERT: A rows = identity, shared weights, Hs[T][SHI]
template<bool EXPERT>
__global__ __launch_bounds__(256) void gemm_dual_kernel(
    const unsigned short* __restrict__ Abase,   // xb [T][DIM] bf16
    const unsigned short* __restrict__ B1base,  // w1t: [e][INTER][DIM] or ws1t [SHI][DIM]
    const unsigned short* __restrict__ B3base,
    unsigned short* __restrict__ Hout,
    const int* __restrict__ counts,
    const int* __restrict__ tok_list) {
  __shared__ __align__(16) unsigned short Abuf[128 * 64];
  __shared__ __align__(16) unsigned short Bbuf[128 * 64];
  const int fc = blockIdx.x, rt = blockIdx.y;
  const int e = EXPERT ? blockIdx.z : 0;
  const int ne = EXPERT ? min(counts[e], CAP) : T_TOK;
  if (rt * 128 >= ne) return;                  // block-uniform, before any barrier
  const int f0 = fc * 64;
  const int tid = threadIdx.x;
  const int lane = tid & 63, wv = tid >> 6;
  const int l15 = lane & 15, l7 = lane & 7, lg = lane >> 4;
  const int subrow = lane >> 3;          // 0..7
  const int koffL = l7 ^ subrow;         // swizzled logical k16 slot (involution)

  const char* gA[4]; const char* gB[4];
  #pragma unroll
  for (int j = 0; j < 4; ++j) {
    const int r = wv * 32 + j * 8 + subrow;      // tile row 0..127
    size_t arow;
    if (EXPERT) {
      int rr = rt * 128 + r;
      int tk = (rr < ne) ? tok_list[e * CAP + rr] : 0;
      arow = (size_t)tk;
    } else {
      arow = (size_t)(rt * 128 + r);
    }
    gA[j] = (const char*)Abase + (arow * DIM + (size_t)koffL * 8) * 2;
    const unsigned short* bb; size_t brow;
    if (r < 64) { bb = B1base; brow = (size_t)(EXPERT ? e * INTER : 0) + f0 + r; }
    else        { bb = B3base; brow = (size_t)(EXPERT ? e * INTER : 0) + f0 + r - 64; }
    gB[j] = (const char*)bb + (brow * DIM + (size_t)koffL * 8) * 2;
  }

  f32x4 acc[4][4];
  #pragma unroll
  for (int m = 0; m < 4; ++m)
    #pragma unroll
    for (int n = 0; n < 4; ++n) acc[m][n] = (f32x4){0.f, 0.f, 0.f, 0.f};

  const int wr = wv >> 1, wc = wv & 1;
  int aRow[4], bRow[4];
  #pragma unroll
  for (int m = 0; m < 4; ++m) aRow[m] = (wr * 64 + m * 16 + l15) * 128;
  #pragma unroll
  for (int n = 0; n < 4; ++n) {
    int br = (n < 2) ? (wc * 32 + n * 16) : (64 + wc * 32 + (n - 2) * 16);
    bRow[n] = (br + l15) * 128;
  }
  char* ldsA = (char*)Abuf; char* ldsB = (char*)Bbuf;
  const int ldsOff = wv * 4096;

  for (int k0 = 0; k0 < DIM; k0 += 64) {
    const size_t kb = (size_t)k0 * 2;
    #pragma unroll
    for (int j = 0; j < 4; ++j) gload16(gA[j] + kb, ldsA + ldsOff + j * 1024);
    #pragma unroll
    for (int j = 0; j < 4; ++j) gload16(gB[j] + kb, ldsB + ldsOff + j * 1024);
    __syncthreads();
    #pragma unroll
    for (int s = 0; s < 2; ++s) {
      const int kslot = (((lg + s * 4) ^ l7) << 4);
      i32x4 af[4], bf_[4];
      #pragma unroll
      for (int m = 0; m < 4; ++m) af[m] = *(const i32x4*)(ldsA + aRow[m] + kslot);
      #pragma unroll
      for (int n = 0; n < 4; ++n) bf_[n] = *(const i32x4*)(ldsB + bRow[n] + kslot);
      #pragma unroll
      for (int m = 0; m < 4; ++m)
        #pragma unroll
        for (int n = 0; n < 4; ++n) mfma16(acc[m][n], af[m], bf_[n]);
    }
    __syncthreads();
  }
  asm volatile("s_nop 7\n\ts_nop 7");   // MFMA->VALU read hazard guard (asm path)
  const int rowbase = rt * 128 + wr * 64 + lg * 4;
  #pragma unroll
  for (int m = 0; m < 4; ++m) {
    #pragma unroll
    for (int n = 0; n < 2; ++n) {
      const int col = f0 + wc * 32 + n * 16 + l15;
      #pragma unroll
      for (int r = 0; r < 4; ++r) {
        const int row = rowbase + m * 16 + r;
        float c1 = acc[m][n][r], c2 = acc[m][n + 2][r];
        float h = (c1 / (1.f + __expf(-c1))) * c2;   // silu(c1)*c2
        size_t off = EXPERT ? ((size_t)(e * CAP + row) * INTER + col)
                            : ((size_t)row * SHI + col);
        Hout[off] = f2bf(h);
      }
    }
  }
}

// ============ GEMM 2: Out[128x128] = A[128xKD] * B[KD x 128], scatter or store ============
template<bool EXPERT, int KD>
__global__ __launch_bounds__(256) void gemm_out_kernel(
    const unsigned short* __restrict__ Abase,   // H [E][CAP][INTER] or Hs [T][SHI]
    const unsigned short* __restrict__ Bbase,   // w2t [e][DIM][INTER] or ws2t [DIM][SHI]
    float* __restrict__ dout,
    const int* __restrict__ counts,
    const int* __restrict__ tok_list,
    const float* __restrict__ wt_list) {
  __shared__ __align__(16) unsigned short Abuf[128 * 64];
  __shared__ __align__(16) unsigned short Bbuf[128 * 64];
  const int nc = blockIdx.x, rt = blockIdx.y;
  const int e = EXPERT ? blockIdx.z : 0;
  const int ne = EXPERT ? min(counts[e], CAP) : T_TOK;
  if (rt * 128 >= ne) return;
  const int n0 = nc * 128;
  const int tid = threadIdx.x;
  const int lane = tid & 63, wv = tid >> 6;
  const int l15 = lane & 15, l7 = lane & 7, lg = lane >> 4;
  const int subrow = lane >> 3;
  const int koffL = l7 ^ subrow;

  const char* gA[4]; const char* gB[4];
  #pragma unroll
  for (int j = 0; j < 4; ++j) {
    const int r = wv * 32 + j * 8 + subrow;
    size_t arow = (size_t)(EXPERT ? e * CAP : 0) + rt * 128 + r;
    gA[j] = (const char*)Abase + (arow * KD + (size_t)koffL * 8) * 2;
    size_t brow = (size_t)(EXPERT ? e * DIM : 0) + n0 + r;
    gB[j] = (const char*)Bbase + (brow * KD + (size_t)koffL * 8) * 2;
  }
  f32x4 acc[4][4];
  #pragma unroll
  for (int m = 0; m < 4; ++m)
    #pragma unroll
    for (int n = 0; n < 4; ++n) acc[m][n] = (f32x4){0.f, 0.f, 0.f, 0.f};
  const int wr = wv >> 1, wc = wv & 1;
  int aRow[4], bRow[4];
  #pragma unroll
  for (int m = 0; m < 4; ++m) aRow[m] = (wr * 64 + m * 16 + l15) * 128;
  #pragma unroll
  for (int n = 0; n < 4; ++n) bRow[n] = (wc * 64 + n * 16 + l15) * 128;
  char* ldsA = (char*)Abuf; char* ldsB = (char*)Bbuf;
  const int ldsOff = wv * 4096;

  for (int k0 = 0; k0 < KD; k0 += 64) {
    const size_t kb = (size_t)k0 * 2;
    #pragma unroll
    for (int j = 0; j < 4; ++j) gload16(gA[j] + kb, ldsA + ldsOff + j * 1024);
    #pragma unroll
    for (int j = 0; j < 4; ++j) gload16(gB[j] + kb, ldsB + ldsOff + j * 1024);
    __syncthreads();
    #pragma unroll
    for (int s = 0; s < 2; ++s) {
      const int kslot = (((lg + s * 4) ^ l7) << 4);
      i32x4 af[4], bf_[4];
      #pragma unroll
      for (int m = 0; m < 4; ++m) af[m] = *(const i32x4*)(ldsA + aRow[m] + kslot);
      #pragma unroll
      for (int n = 0; n < 4; ++n) bf_[n] = *(const i32x4*)(ldsB + bRow[n] + kslot);
      #pragma unroll
      for (int m = 0; m < 4; ++m)
        #pragma unroll
        for (int n = 0; n < 4; ++n) mfma16(acc[m][n], af[m], bf_[n]);
    }
    __syncthreads();
  }
  asm volatile("s_nop 7\n\ts_nop 7");
  #pragma unroll
  for (int m = 0; m < 4; ++m) {
    const int rowl = wr * 64 + m * 16 + lg * 4;
    #pragma unroll
    for (int r = 0; r < 4; ++r) {
      const int rr = rt * 128 + rowl + r;
      int tk = 0; float wt = 0.f;
      bool valid = true;
      if (EXPERT) {
        valid = (rr < ne);
        if (valid) { tk = tok_list[e * CAP + rr]; wt = wt_list[e * CAP + rr]; }
      }
      #pragma unroll
      for (int n = 0; n < 4; ++n) {
        const int col = n0 + wc * 64 + n * 16 + l15;
        float v = acc[m][n][r];
        if (EXPERT) {
          if (valid) atomicAdd(&dout[(size_t)tk * DIM + col], v * wt);
        } else {
          dout[(size_t)rr * DIM + col] = v;
        }
      }
    }
  }
}

// ---------------- launch ----------------
extern "C" void kernel_launch(void* const* d_in, const int* in_sizes, int n_in,
                              void* d_out, int out_size, void* d_ws, size_t ws_size,
                              hipStream_t stream) {
  const float* x   = (const float*)d_in[0];
  const float* gw  = (const float*)d_in[1];
  const float* w1  = (const float*)d_in[2];
  const float* w2  = (const float*)d_in[3];
  const float* w3  = (const float*)d_in[4];
  const float* ws1 = (const float*)d_in[5];
  const float* ws2 = (const float*)d_in[6];
  const float* ws3 = (const float*)d_in[7];
  float* out = (float*)d_out;
  char* ws = (char*)d_ws;
  size_t o = 0;
  auto carve = [&](size_t b) { o = (o + 255) & ~(size_t)255; char* p = ws + o; o += b; return p; };

  unsigned short* xb   = (unsigned short*)carve((size_t)T_TOK * DIM * 2);
  unsigned short* w1t  = (unsigned short*)carve((size_t)NEXP * INTER * DIM * 2);
  unsigned short* w3t  = (unsigned short*)carve((size_t)NEXP * INTER * DIM * 2);
  unsigned short* w2t  = (unsigned short*)carve((size_t)NEXP * DIM * INTER * 2);
  unsigned short* ws1t = (unsigned short*)carve((size_t)SHI * DIM * 2);
  unsigned short* ws3t = (unsigned short*)carve((size_t)SHI * DIM * 2);
  unsigned short* ws2t = (unsigned short*)carve((size_t)DIM * SHI * 2);
  float* scores = (float*)carve((size_t)T_TOK * NEXP * 4);
  int*   counts = (int*)carve(256);
  int*   tok    = (int*)carve((size_t)NEXP * CAP * 4);
  float* wt     = (float*)carve((size_t)NEXP * CAP * 4);
  unsigned short* H  = (unsigned short*)carve((size_t)NEXP * CAP * INTER * 2);
  unsigned short* Hs = (unsigned short*)carve((size_t)T_TOK * SHI * 2);

  // prep: bf16 conversions + weight transposes
  cvt_x_kernel<<<T_TOK * DIM / 4 / 256, 256, 0, stream>>>((const float4*)x, (uint2*)xb);
  transpose_cvt<<<dim3(INTER / 32, DIM / 32, NEXP), 256, 0, stream>>>(w1, w1t, DIM, INTER);
  transpose_cvt<<<dim3(INTER / 32, DIM / 32, NEXP), 256, 0, stream>>>(w3, w3t, DIM, INTER);
  transpose_cvt<<<dim3(DIM / 32, INTER / 32, NEXP), 256, 0, stream>>>(w2, w2t, INTER, DIM);
  transpose_cvt<<<dim3(SHI / 32, DIM / 32, 1), 256, 0, stream>>>(ws1, ws1t, DIM, SHI);
  transpose_cvt<<<dim3(SHI / 32, DIM / 32, 1), 256, 0, stream>>>(ws3, ws3t, DIM, SHI);
  transpose_cvt<<<dim3(DIM / 32, SHI / 32, 1), 256, 0, stream>>>(ws2, ws2t, SHI, DIM);

  // gate + routing (fp32 exact)
  gate_kernel<<<T_TOK / 16, 256, 0, stream>>>(x, gw, scores);
  zero_counts_kernel<<<1, NEXP, 0, stream>>>(counts);
  route_kernel<<<T_TOK / 256, 256, 0, stream>>>(scores, counts, tok, wt);

  // shared experts first (plain stores into d_out), then routed experts (atomic adds)
  gemm_dual_kernel<false><<<dim3(SHI / 64, T_TOK / 128, 1), 256, 0, stream>>>(
      xb, ws1t, ws3t, Hs, nullptr, nullptr);
  gemm_out_kernel<false, SHI><<<dim3(DIM / 128, T_TOK / 128, 1), 256, 0, stream>>>(
      Hs, ws2t, out, nullptr, nullptr, nullptr);
  gemm_dual_kernel<true><<<dim3(INTER / 64, CAP / 128, NEXP), 256, 0, stream>>>(
      xb, w1t, w3t, H, counts, tok);
  gemm_out_kernel<true, INTER><<<dim3(DIM / 128, CAP / 128, NEXP), 256, 0, stream>>>(
      H, w2t, out, counts, tok, wt);
}